// Round 1
// baseline (717.240 us; speedup 1.0000x reference)
//
#include <hip/hip_runtime.h>
#include <hip/hip_bf16.h>

#define N_FULL 262144
#define M_POOL 131072

typedef __attribute__((ext_vector_type(4))) float f32x4;
typedef __attribute__((ext_vector_type(8))) short bf16x8;

__device__ __forceinline__ unsigned short f2b(float f) {
    __hip_bfloat16 b = __float2bfloat16(f);
    return *reinterpret_cast<unsigned short*>(&b);
}

// ---------- pack weights into MFMA B-fragment order ----------
// Wp[k][q][t][lane][j] = W[k][q*32 + (lane>>4)*8 + j][t*16 + (lane&15)]
template<int CT>
__global__ __launch_bounds__(256) void pack_w_kernel(const float* __restrict__ W,
                                                     unsigned short* __restrict__ Wp) {
    int i = blockIdx.x * 256 + threadIdx.x;
    const int total = 27 * 2 * CT * 64 * 8;
    if (i >= total) return;
    int j = i & 7;
    int l = (i >> 3) & 63;
    int t = (i >> 9) % CT;
    int q = (i / (512 * CT)) & 1;
    int k = i / (1024 * CT);
    int cin = q * 32 + (l >> 4) * 8 + j;
    int cout = t * 16 + (l & 15);
    Wp[i] = f2b(W[(k * 64 + cin) * (CT * 16) + cout]);
}

// ---------- conv1: Cin=3, Cout=64, VALU fp32, wave-per-row ----------
__global__ __launch_bounds__(256) void conv1_kernel(const float* __restrict__ feats,
                                                    const float* __restrict__ W1,
                                                    const int* __restrict__ nbr,
                                                    float* __restrict__ Y, int R) {
    __shared__ float w[27 * 3 * 64];
    for (int i = threadIdx.x; i < 27 * 3 * 64; i += 256) w[i] = W1[i];
    __syncthreads();
    const int lane = threadIdx.x & 63;
    const int gw = blockIdx.x * 4 + (threadIdx.x >> 6);
    const int nw = gridDim.x * 4;
    for (int r = gw; r < R; r += nw) {
        float acc = 0.f;
        for (int kb = 0; kb < 27; kb += 9) {
            int idxs[9];
            #pragma unroll
            for (int u = 0; u < 9; ++u) idxs[u] = nbr[(kb + u) * R + r];
            #pragma unroll
            for (int u = 0; u < 9; ++u) {
                int idx = idxs[u];
                if (idx >= 0) {  // wave-uniform branch (all lanes share r)
                    float f0 = feats[idx * 3 + 0];
                    float f1 = feats[idx * 3 + 1];
                    float f2 = feats[idx * 3 + 2];
                    const float* wk = &w[(kb + u) * 192 + lane];
                    acc += f0 * wk[0] + f1 * wk[64] + f2 * wk[128];
                }
            }
        }
        Y[r * 64 + lane] = acc;
    }
}

// ---------- MFMA sparse conv: Cin=64, Cout=CT*16 ----------
// block = 4 waves, 128 output rows; wave owns 32 rows (2 subtiles of 16)
template<int CT>
__global__ __launch_bounds__(256) void conv_mfma_kernel(const unsigned short* __restrict__ X,
                                                        const unsigned short* __restrict__ Wp,
                                                        const int* __restrict__ nbr,
                                                        float* __restrict__ Y, int Nout) {
    __shared__ unsigned short lw[2 * CT * 64 * 8];
    const int tid = threadIdx.x;
    const int wave = tid >> 6;
    const int lane = tid & 63;
    const int l16 = lane & 15;
    const int lq = lane >> 4;
    const int rowbase = blockIdx.x * 128 + wave * 32;

    f32x4 acc[2][CT];
    #pragma unroll
    for (int s = 0; s < 2; ++s)
        #pragma unroll
        for (int t = 0; t < CT; ++t)
            #pragma unroll
            for (int g = 0; g < 4; ++g) acc[s][t][g] = 0.f;

    bf16x8 zfrag;
    #pragma unroll
    for (int j = 0; j < 8; ++j) zfrag[j] = 0;

    for (int k = 0; k < 27; ++k) {
        __syncthreads();  // protect lw from previous iteration's readers
        // stage B = Wp[k] into LDS (CT*2048 bytes), coalesced int4 copies
        {
            const int4* src = reinterpret_cast<const int4*>(Wp + k * (2 * CT * 512));
            int4* dst = reinterpret_cast<int4*>(lw);
            #pragma unroll
            for (int i = 0; i < CT * 128; i += 256) dst[i + tid] = src[i + tid];
        }
        // gather A fragments straight from global (per-lane predicated)
        bf16x8 afr[2][2];
        #pragma unroll
        for (int s = 0; s < 2; ++s) {
            int idx = nbr[k * Nout + rowbase + s * 16 + l16];
            #pragma unroll
            for (int q = 0; q < 2; ++q) {
                if (idx >= 0)
                    afr[s][q] = *reinterpret_cast<const bf16x8*>(X + idx * 64 + q * 32 + lq * 8);
                else
                    afr[s][q] = zfrag;
            }
        }
        __syncthreads();  // staging visible
        #pragma unroll
        for (int t = 0; t < CT; ++t) {
            #pragma unroll
            for (int q = 0; q < 2; ++q) {
                bf16x8 bfr = *reinterpret_cast<const bf16x8*>(&lw[((q * CT + t) * 64 + lane) * 8]);
                #pragma unroll
                for (int s = 0; s < 2; ++s)
                    acc[s][t] = __builtin_amdgcn_mfma_f32_16x16x32_bf16(afr[s][q], bfr, acc[s][t], 0, 0, 0);
            }
        }
    }
    // epilogue: D layout col=lane&15, row=(lane>>4)*4+g
    #pragma unroll
    for (int s = 0; s < 2; ++s)
        #pragma unroll
        for (int t = 0; t < CT; ++t)
            #pragma unroll
            for (int g = 0; g < 4; ++g)
                Y[(rowbase + s * 16 + lq * 4 + g) * (CT * 16) + t * 16 + l16] = acc[s][t][g];
}

// ---------- per-channel sum/sumsq reduction ----------
template<int C>
__global__ __launch_bounds__(256) void reduce_kernel(const float* __restrict__ Y,
                                                     float* __restrict__ sums, int R) {
    constexpr int S = 256 / C;
    const int c = threadIdx.x % C;
    const int sl = threadIdx.x / C;
    float s = 0.f, s2 = 0.f;
    for (int r = blockIdx.x * S + sl; r < R; r += gridDim.x * S) {
        float v = Y[r * C + c];
        s += v;
        s2 += v * v;
    }
    __shared__ float ls[256], lsq[256];
    ls[threadIdx.x] = s;
    lsq[threadIdx.x] = s2;
    __syncthreads();
    if (sl == 0) {
        #pragma unroll
        for (int i = 1; i < S; ++i) { s += ls[i * C + c]; s2 += lsq[i * C + c]; }
        atomicAdd(&sums[c], s);
        atomicAdd(&sums[C + c], s2);
    }
}

// ---------- normalize + relu -> bf16 ----------
template<int C>
__global__ __launch_bounds__(256) void norm_bf16_kernel(const float* __restrict__ Y,
                                                        const float* __restrict__ sums,
                                                        unsigned short* __restrict__ Xb, int R) {
    __shared__ float lmu[C], lrs[C];
    if (threadIdx.x < C) {
        float m = sums[threadIdx.x] / (float)R;
        float v = sums[C + threadIdx.x] / (float)R - m * m;
        lmu[threadIdx.x] = m;
        lrs[threadIdx.x] = rsqrtf(fmaxf(v, 0.f) + 1e-5f);
    }
    __syncthreads();
    const int total = R * C / 4;
    for (int i = blockIdx.x * 256 + threadIdx.x; i < total; i += gridDim.x * 256) {
        float4 v = reinterpret_cast<const float4*>(Y)[i];
        int cb = (i * 4) & (C - 1);
        ushort4 o;
        o.x = f2b(fmaxf((v.x - lmu[cb + 0]) * lrs[cb + 0], 0.f));
        o.y = f2b(fmaxf((v.y - lmu[cb + 1]) * lrs[cb + 1], 0.f));
        o.z = f2b(fmaxf((v.z - lmu[cb + 2]) * lrs[cb + 2], 0.f));
        o.w = f2b(fmaxf((v.w - lmu[cb + 3]) * lrs[cb + 3], 0.f));
        reinterpret_cast<ushort4*>(Xb)[i] = o;
    }
}

// ---------- normalize + relu -> f32 (final output) ----------
template<int C>
__global__ __launch_bounds__(256) void norm_f32_kernel(const float* __restrict__ Y,
                                                       const float* __restrict__ sums,
                                                       float* __restrict__ Out, int R) {
    __shared__ float lmu[C], lrs[C];
    if (threadIdx.x < C) {
        float m = sums[threadIdx.x] / (float)R;
        float v = sums[C + threadIdx.x] / (float)R - m * m;
        lmu[threadIdx.x] = m;
        lrs[threadIdx.x] = rsqrtf(fmaxf(v, 0.f) + 1e-5f);
    }
    __syncthreads();
    const int total = R * C / 4;
    for (int i = blockIdx.x * 256 + threadIdx.x; i < total; i += gridDim.x * 256) {
        float4 v = reinterpret_cast<const float4*>(Y)[i];
        int cb = (i * 4) & (C - 1);
        float4 o;
        o.x = fmaxf((v.x - lmu[cb + 0]) * lrs[cb + 0], 0.f);
        o.y = fmaxf((v.y - lmu[cb + 1]) * lrs[cb + 1], 0.f);
        o.z = fmaxf((v.z - lmu[cb + 2]) * lrs[cb + 2], 0.f);
        o.w = fmaxf((v.w - lmu[cb + 3]) * lrs[cb + 3], 0.f);
        reinterpret_cast<float4*>(Out)[i] = o;
    }
}

// ---------- max-pool (raw) then normalize+relu -> bf16 ----------
// valid because norm (rstd>0) and relu are monotone increasing: pool-then-norm == norm-then-pool
__global__ __launch_bounds__(256) void pool_norm_kernel(const float* __restrict__ Y2,
                                                        const int* __restrict__ pmap,
                                                        const float* __restrict__ sums,
                                                        unsigned short* __restrict__ Xp,
                                                        int M, int R) {
    __shared__ float lmu[64], lrs[64];
    if (threadIdx.x < 64) {
        float m = sums[threadIdx.x] / (float)R;
        float v = sums[64 + threadIdx.x] / (float)R - m * m;
        lmu[threadIdx.x] = m;
        lrs[threadIdx.x] = rsqrtf(fmaxf(v, 0.f) + 1e-5f);
    }
    __syncthreads();
    const int lane = threadIdx.x & 63;
    const int gw = blockIdx.x * 4 + (threadIdx.x >> 6);
    const int nw = gridDim.x * 4;
    for (int m = gw; m < M; m += nw) {
        float best = -INFINITY;
        #pragma unroll
        for (int o = 0; o < 8; ++o) {
            int idx = pmap[o * M + m];
            if (idx >= 0) best = fmaxf(best, Y2[idx * 64 + lane]);  // wave-uniform branch
        }
        Xp[m * 64 + lane] = f2b(fmaxf((best - lmu[lane]) * lrs[lane], 0.f));
    }
}

extern "C" void kernel_launch(void* const* d_in, const int* in_sizes, int n_in,
                              void* d_out, int out_size, void* d_ws, size_t ws_size,
                              hipStream_t stream) {
    const float* feats = (const float*)d_in[0];
    const float* W1 = (const float*)d_in[1];
    const float* W2 = (const float*)d_in[2];
    const float* W3 = (const float*)d_in[3];
    const int* nbr1 = (const int*)d_in[4];
    const int* pmap = (const int*)d_in[5];
    const int* nbr2 = (const int*)d_in[6];
    float* out = (float*)d_out;

    const int N = N_FULL, M = M_POOL;
    char* ws = (char*)d_ws;
    // ws layout (aliased across stages): y (f32 N*64, holds y1 then y2 then y3),
    // xb (bf16 N*64, holds x1 then pooled x), packed weights, sums.  ~101 MB total.
    float* y = (float*)ws;
    unsigned short* xb = (unsigned short*)(ws + (size_t)N * 64 * 4);
    unsigned short* w2p = xb + (size_t)N * 64;
    unsigned short* w3p = w2p + 27 * 64 * 64;
    float* sums = (float*)(w3p + 27 * 64 * 128);
    float* sums1 = sums;
    float* sums2 = sums + 128;
    float* sums3 = sums + 256;

    hipMemsetAsync(sums, 0, 512 * sizeof(float), stream);
    pack_w_kernel<4><<<(27 * 4096 + 255) / 256, 256, 0, stream>>>(W2, w2p);
    pack_w_kernel<8><<<(27 * 8192 + 255) / 256, 256, 0, stream>>>(W3, w3p);

    conv1_kernel<<<2048, 256, 0, stream>>>(feats, W1, nbr1, y, N);
    reduce_kernel<64><<<1024, 256, 0, stream>>>(y, sums1, N);
    norm_bf16_kernel<64><<<2048, 256, 0, stream>>>(y, sums1, xb, N);

    conv_mfma_kernel<4><<<N / 128, 256, 0, stream>>>(xb, w2p, nbr1, y, N);
    reduce_kernel<64><<<1024, 256, 0, stream>>>(y, sums2, N);
    pool_norm_kernel<<<1024, 256, 0, stream>>>(y, pmap, sums2, xb, M, N);

    conv_mfma_kernel<8><<<M / 128, 256, 0, stream>>>(xb, w3p, nbr2, y, M);
    reduce_kernel<128><<<1024, 256, 0, stream>>>(y, sums3, M);
    norm_f32_kernel<128><<<2048, 256, 0, stream>>>(y, sums3, out, M);
}

// Round 2
// 524.280 us; speedup vs baseline: 1.3680x; 1.3680x over previous
//
#include <hip/hip_runtime.h>
#include <hip/hip_bf16.h>

#define N_FULL 262144
#define M_POOL 131072

typedef __attribute__((ext_vector_type(4))) float f32x4;
typedef __attribute__((ext_vector_type(8))) short bf16x8;
typedef __attribute__((ext_vector_type(8))) unsigned short u16x8;

__device__ __forceinline__ unsigned short f2b(float f) {
    __hip_bfloat16 b = __float2bfloat16(f);
    return *reinterpret_cast<unsigned short*>(&b);
}
__device__ __forceinline__ float b2f(unsigned short u) {
    unsigned int x = ((unsigned int)u) << 16;
    return __uint_as_float(x);
}

// ---------- pack W2/W3 into MFMA B-fragment order ----------
// Wp[k][q][t][lane][j] = W[k][q*32 + (lane>>4)*8 + j][t*16 + (lane&15)]
template<int CT>
__global__ __launch_bounds__(256) void pack_w_kernel(const float* __restrict__ W,
                                                     unsigned short* __restrict__ Wp) {
    int i = blockIdx.x * 256 + threadIdx.x;
    const int total = 27 * 2 * CT * 64 * 8;
    if (i >= total) return;
    int j = i & 7;
    int l = (i >> 3) & 63;
    int t = (i >> 9) % CT;
    int q = (i / (512 * CT)) & 1;
    int k = i / (1024 * CT);
    int cin = q * 32 + (l >> 4) * 8 + j;
    int cout = t * 16 + (l & 15);
    Wp[i] = f2b(W[(k * 64 + cin) * (CT * 16) + cout]);
}

// ---------- pack W1 (Cin=3) with 4 taps folded into K=32 ----------
// Wp1[kb][t][lane][j]: tap = kb*4 + (lane>>4), cin = j (<3), cout = t*16+(lane&15)
__global__ __launch_bounds__(256) void pack_w1_kernel(const float* __restrict__ W1,
                                                      unsigned short* __restrict__ Wp) {
    int i = blockIdx.x * 256 + threadIdx.x;
    const int total = 7 * 4 * 64 * 8;
    if (i >= total) return;
    int j = i & 7;
    int l = (i >> 3) & 63;
    int t = (i >> 9) & 3;
    int kb = i >> 11;
    int tap = kb * 4 + (l >> 4);
    float v = 0.f;
    if (tap < 27 && j < 3) v = W1[(tap * 3 + j) * 64 + t * 16 + (l & 15)];
    Wp[i] = f2b(v);
}

// ---------- conv1: MFMA, 4 taps per K=32, fused stats ----------
__global__ __launch_bounds__(256) void conv1_mfma_kernel(const float* __restrict__ feats,
                                                         const unsigned short* __restrict__ Wp,
                                                         const int* __restrict__ nbr,
                                                         unsigned short* __restrict__ Y,
                                                         float* __restrict__ sums, int R) {
    __shared__ unsigned short lw[4 * 64 * 8];   // 4 KB per tap-group
    __shared__ float psum[4][64], psq[4][64];
    const int tid = threadIdx.x;
    const int wave = tid >> 6;
    const int lane = tid & 63;
    const int l16 = lane & 15;
    const int lq = lane >> 4;
    const int rowbase = blockIdx.x * 128 + wave * 32;

    f32x4 acc[2][4];
    #pragma unroll
    for (int s = 0; s < 2; ++s)
        #pragma unroll
        for (int t = 0; t < 4; ++t)
            #pragma unroll
            for (int g = 0; g < 4; ++g) acc[s][t][g] = 0.f;

    bf16x8 zfrag;
    #pragma unroll
    for (int j = 0; j < 8; ++j) zfrag[j] = 0;

    for (int kb = 0; kb < 7; ++kb) {
        __syncthreads();
        // stage B group (4 KB = 256 x int4)
        reinterpret_cast<int4*>(lw)[tid] =
            reinterpret_cast<const int4*>(Wp + kb * 2048)[tid];
        // gather A: lane holds row=l16, tap=kb*4+lq, channels j<3
        const int tap = kb * 4 + lq;
        bf16x8 afr[2];
        #pragma unroll
        for (int s = 0; s < 2; ++s) {
            afr[s] = zfrag;
            int idx = (tap < 27) ? nbr[tap * R + rowbase + s * 16 + l16] : -1;
            if (idx >= 0) {
                afr[s][0] = (short)f2b(feats[idx * 3 + 0]);
                afr[s][1] = (short)f2b(feats[idx * 3 + 1]);
                afr[s][2] = (short)f2b(feats[idx * 3 + 2]);
            }
        }
        __syncthreads();
        #pragma unroll
        for (int t = 0; t < 4; ++t) {
            bf16x8 bfr = *reinterpret_cast<const bf16x8*>(&lw[(t * 64 + lane) * 8]);
            #pragma unroll
            for (int s = 0; s < 2; ++s)
                acc[s][t] = __builtin_amdgcn_mfma_f32_16x16x32_bf16(afr[s], bfr, acc[s][t], 0, 0, 0);
        }
    }
    // store bf16 + fused per-channel stats
    #pragma unroll
    for (int t = 0; t < 4; ++t) {
        float s1 = 0.f, s2 = 0.f;
        #pragma unroll
        for (int s = 0; s < 2; ++s)
            #pragma unroll
            for (int g = 0; g < 4; ++g) {
                float v = acc[s][t][g];
                s1 += v; s2 += v * v;
                Y[(rowbase + s * 16 + lq * 4 + g) * 64 + t * 16 + l16] = f2b(v);
            }
        s1 += __shfl_xor(s1, 16); s2 += __shfl_xor(s2, 16);
        s1 += __shfl_xor(s1, 32); s2 += __shfl_xor(s2, 32);
        if (lq == 0) { psum[wave][t * 16 + l16] = s1; psq[wave][t * 16 + l16] = s2; }
    }
    __syncthreads();
    if (tid < 64) {
        float s1 = 0.f, s2 = 0.f;
        #pragma unroll
        for (int w = 0; w < 4; ++w) { s1 += psum[w][tid]; s2 += psq[w][tid]; }
        atomicAdd(&sums[tid], s1);
        atomicAdd(&sums[64 + tid], s2);
    }
}

// ---------- MFMA sparse conv: Cin=64, Cout=CT*16, fused stats, bf16 out ----------
template<int CT>
__global__ __launch_bounds__(256) void conv_mfma_kernel(const unsigned short* __restrict__ X,
                                                        const unsigned short* __restrict__ Wp,
                                                        const int* __restrict__ nbr,
                                                        unsigned short* __restrict__ Y,
                                                        float* __restrict__ sums, int Nout) {
    __shared__ unsigned short lw[2 * CT * 64 * 8];
    __shared__ float psum[4][CT * 16], psq[4][CT * 16];
    const int tid = threadIdx.x;
    const int wave = tid >> 6;
    const int lane = tid & 63;
    const int l16 = lane & 15;
    const int lq = lane >> 4;
    const int rowbase = blockIdx.x * 128 + wave * 32;
    constexpr int C = CT * 16;

    f32x4 acc[2][CT];
    #pragma unroll
    for (int s = 0; s < 2; ++s)
        #pragma unroll
        for (int t = 0; t < CT; ++t)
            #pragma unroll
            for (int g = 0; g < 4; ++g) acc[s][t][g] = 0.f;

    bf16x8 zfrag;
    #pragma unroll
    for (int j = 0; j < 8; ++j) zfrag[j] = 0;

    for (int k = 0; k < 27; ++k) {
        __syncthreads();
        {
            const int4* src = reinterpret_cast<const int4*>(Wp + k * (2 * CT * 512));
            int4* dst = reinterpret_cast<int4*>(lw);
            #pragma unroll
            for (int i = 0; i < CT * 128; i += 256) dst[i + tid] = src[i + tid];
        }
        bf16x8 afr[2][2];
        #pragma unroll
        for (int s = 0; s < 2; ++s) {
            int idx = nbr[k * Nout + rowbase + s * 16 + l16];
            #pragma unroll
            for (int q = 0; q < 2; ++q) {
                if (idx >= 0)
                    afr[s][q] = *reinterpret_cast<const bf16x8*>(X + idx * 64 + q * 32 + lq * 8);
                else
                    afr[s][q] = zfrag;
            }
        }
        __syncthreads();
        #pragma unroll
        for (int t = 0; t < CT; ++t) {
            #pragma unroll
            for (int q = 0; q < 2; ++q) {
                bf16x8 bfr = *reinterpret_cast<const bf16x8*>(&lw[((q * CT + t) * 64 + lane) * 8]);
                #pragma unroll
                for (int s = 0; s < 2; ++s)
                    acc[s][t] = __builtin_amdgcn_mfma_f32_16x16x32_bf16(afr[s][q], bfr, acc[s][t], 0, 0, 0);
            }
        }
    }
    #pragma unroll
    for (int t = 0; t < CT; ++t) {
        float s1 = 0.f, s2 = 0.f;
        #pragma unroll
        for (int s = 0; s < 2; ++s)
            #pragma unroll
            for (int g = 0; g < 4; ++g) {
                float v = acc[s][t][g];
                s1 += v; s2 += v * v;
                Y[(rowbase + s * 16 + lq * 4 + g) * C + t * 16 + l16] = f2b(v);
            }
        s1 += __shfl_xor(s1, 16); s2 += __shfl_xor(s2, 16);
        s1 += __shfl_xor(s1, 32); s2 += __shfl_xor(s2, 32);
        if (lq == 0) { psum[wave][t * 16 + l16] = s1; psq[wave][t * 16 + l16] = s2; }
    }
    __syncthreads();
    if (tid < C) {
        float s1 = 0.f, s2 = 0.f;
        #pragma unroll
        for (int w = 0; w < 4; ++w) { s1 += psum[w][tid]; s2 += psq[w][tid]; }
        atomicAdd(&sums[tid], s1);
        atomicAdd(&sums[C + tid], s2);
    }
}

// ---------- normalize + relu : bf16 in -> bf16 out ----------
template<int C>
__global__ __launch_bounds__(256) void norm_bf16_kernel(const unsigned short* __restrict__ Y,
                                                        const float* __restrict__ sums,
                                                        unsigned short* __restrict__ Xb, int R) {
    __shared__ float lmu[C], lrs[C];
    if (threadIdx.x < C) {
        float m = sums[threadIdx.x] / (float)R;
        float v = sums[C + threadIdx.x] / (float)R - m * m;
        lmu[threadIdx.x] = m;
        lrs[threadIdx.x] = rsqrtf(fmaxf(v, 0.f) + 1e-5f);
    }
    __syncthreads();
    const int total = R * C / 8;
    for (int i = blockIdx.x * 256 + threadIdx.x; i < total; i += gridDim.x * 256) {
        u16x8 v = reinterpret_cast<const u16x8*>(Y)[i];
        int cb = (i * 8) & (C - 1);
        u16x8 o;
        #pragma unroll
        for (int j = 0; j < 8; ++j) {
            float f = b2f(v[j]);
            o[j] = f2b(fmaxf((f - lmu[cb + j]) * lrs[cb + j], 0.f));
        }
        reinterpret_cast<u16x8*>(Xb)[i] = o;
    }
}

// ---------- normalize + relu : bf16 in -> f32 out (final) ----------
template<int C>
__global__ __launch_bounds__(256) void norm_f32_kernel(const unsigned short* __restrict__ Y,
                                                       const float* __restrict__ sums,
                                                       float* __restrict__ Out, int R) {
    __shared__ float lmu[C], lrs[C];
    if (threadIdx.x < C) {
        float m = sums[threadIdx.x] / (float)R;
        float v = sums[C + threadIdx.x] / (float)R - m * m;
        lmu[threadIdx.x] = m;
        lrs[threadIdx.x] = rsqrtf(fmaxf(v, 0.f) + 1e-5f);
    }
    __syncthreads();
    const int total = R * C / 8;
    for (int i = blockIdx.x * 256 + threadIdx.x; i < total; i += gridDim.x * 256) {
        u16x8 v = reinterpret_cast<const u16x8*>(Y)[i];
        int cb = (i * 8) & (C - 1);
        float4 o0, o1;
        o0.x = fmaxf((b2f(v[0]) - lmu[cb + 0]) * lrs[cb + 0], 0.f);
        o0.y = fmaxf((b2f(v[1]) - lmu[cb + 1]) * lrs[cb + 1], 0.f);
        o0.z = fmaxf((b2f(v[2]) - lmu[cb + 2]) * lrs[cb + 2], 0.f);
        o0.w = fmaxf((b2f(v[3]) - lmu[cb + 3]) * lrs[cb + 3], 0.f);
        o1.x = fmaxf((b2f(v[4]) - lmu[cb + 4]) * lrs[cb + 4], 0.f);
        o1.y = fmaxf((b2f(v[5]) - lmu[cb + 5]) * lrs[cb + 5], 0.f);
        o1.z = fmaxf((b2f(v[6]) - lmu[cb + 6]) * lrs[cb + 6], 0.f);
        o1.w = fmaxf((b2f(v[7]) - lmu[cb + 7]) * lrs[cb + 7], 0.f);
        reinterpret_cast<float4*>(Out)[i * 2] = o0;
        reinterpret_cast<float4*>(Out)[i * 2 + 1] = o1;
    }
}

// ---------- max-pool raw conv2 output, then normalize+relu -> bf16 ----------
// valid: inst_norm (rstd>0) and relu are monotone increasing, so pool-then-norm == norm-then-pool
__global__ __launch_bounds__(256) void pool_norm_kernel(const unsigned short* __restrict__ Y2,
                                                        const int* __restrict__ pmap,
                                                        const float* __restrict__ sums,
                                                        unsigned short* __restrict__ Xp,
                                                        int M, int R) {
    __shared__ float lmu[64], lrs[64];
    if (threadIdx.x < 64) {
        float m = sums[threadIdx.x] / (float)R;
        float v = sums[64 + threadIdx.x] / (float)R - m * m;
        lmu[threadIdx.x] = m;
        lrs[threadIdx.x] = rsqrtf(fmaxf(v, 0.f) + 1e-5f);
    }
    __syncthreads();
    const int lane = threadIdx.x & 63;
    const int gw = blockIdx.x * 4 + (threadIdx.x >> 6);
    const int nw = gridDim.x * 4;
    for (int m = gw; m < M; m += nw) {
        float best = -INFINITY;
        #pragma unroll
        for (int o = 0; o < 8; ++o) {
            int idx = pmap[o * M + m];
            if (idx >= 0) best = fmaxf(best, b2f(Y2[idx * 64 + lane]));  // wave-uniform branch
        }
        Xp[m * 64 + lane] = f2b(fmaxf((best - lmu[lane]) * lrs[lane], 0.f));
    }
}

extern "C" void kernel_launch(void* const* d_in, const int* in_sizes, int n_in,
                              void* d_out, int out_size, void* d_ws, size_t ws_size,
                              hipStream_t stream) {
    const float* feats = (const float*)d_in[0];
    const float* W1 = (const float*)d_in[1];
    const float* W2 = (const float*)d_in[2];
    const float* W3 = (const float*)d_in[3];
    const int* nbr1 = (const int*)d_in[4];
    const int* pmap = (const int*)d_in[5];
    const int* nbr2 = (const int*)d_in[6];
    float* out = (float*)d_out;

    const int N = N_FULL, M = M_POOL;
    char* ws = (char*)d_ws;
    // ws: yb (bf16 N*64 — y1, then y2, then y3), xb (bf16 N*64 — x1, then pooled x),
    // packed weights, sums. ~68 MB.
    unsigned short* yb = (unsigned short*)ws;
    unsigned short* xb = yb + (size_t)N * 64;
    unsigned short* w1p = xb + (size_t)N * 64;
    unsigned short* w2p = w1p + 7 * 4 * 64 * 8;
    unsigned short* w3p = w2p + 27 * 64 * 64;
    float* sums = (float*)(w3p + 27 * 64 * 128);
    float* sums1 = sums;
    float* sums2 = sums + 128;
    float* sums3 = sums + 256;

    hipMemsetAsync(sums, 0, 512 * sizeof(float), stream);
    pack_w1_kernel<<<(7 * 2048 + 255) / 256, 256, 0, stream>>>(W1, w1p);
    pack_w_kernel<4><<<(27 * 4096 + 255) / 256, 256, 0, stream>>>(W2, w2p);
    pack_w_kernel<8><<<(27 * 8192 + 255) / 256, 256, 0, stream>>>(W3, w3p);

    conv1_mfma_kernel<<<N / 128, 256, 0, stream>>>(feats, w1p, nbr1, yb, sums1, N);
    norm_bf16_kernel<64><<<2048, 256, 0, stream>>>(yb, sums1, xb, N);

    conv_mfma_kernel<4><<<N / 128, 256, 0, stream>>>(xb, w2p, nbr1, yb, sums2, N);
    pool_norm_kernel<<<1024, 256, 0, stream>>>(yb, pmap, sums2, xb, M, N);

    conv_mfma_kernel<8><<<M / 128, 256, 0, stream>>>(xb, w3p, nbr2, yb, sums3, M);
    norm_f32_kernel<128><<<2048, 256, 0, stream>>>(yb, sums3, out, M);
}